// Round 6
// baseline (394.504 us; speedup 1.0000x reference)
//
#include <hip/hip_runtime.h>

#define NA 4096
#define NB 4096
#define DIM 256
#define DK 64
#define PBLK 1040        // partial block: 16*64 num + 16 den (floats)
#define LOG2E 1.4426950408889634f
#define CLIP2 14.426950408889634f   // 10 * log2(e)
#define EXPM10 4.5399929e-05f       // exp(-10)

typedef __attribute__((ext_vector_type(8))) short bf16x8;
typedef __attribute__((ext_vector_type(4))) float f32x4;
typedef __attribute__((ext_vector_type(4))) unsigned short us4;
typedef __attribute__((ext_vector_type(4))) int i32x4;

static __device__ __forceinline__ float bf2f(unsigned short u) {
    union { unsigned int u; float f; } x;
    x.u = ((unsigned int)u) << 16;
    return x.f;
}
static __device__ __forceinline__ unsigned short f2bf(float f) {
    union { float f; unsigned int u; } x;
    x.f = f;
    unsigned int r = x.u + 0x7fffu + ((x.u >> 16) & 1u);
    return (unsigned short)(r >> 16);
}
static __device__ __forceinline__ unsigned int asuint(float f) {
    union { float f; unsigned int u; } x; x.f = f; return x.u;
}

// ---------------------------------------------------------------------------
// Pre-split: fp32 -> bf16 hi + lo correction, coalesced elementwise.
// ---------------------------------------------------------------------------
__global__ __launch_bounds__(256) void split_kernel(
    const float* __restrict__ a_z, const float* __restrict__ bv_z,
    const float* __restrict__ Wq, const float* __restrict__ Wk,
    const float* __restrict__ Wv,
    unsigned short* __restrict__ ah, unsigned short* __restrict__ al,
    unsigned short* __restrict__ bh, unsigned short* __restrict__ bl,
    unsigned short* __restrict__ wparts)
{
    const int seg = blockIdx.y;
    const float* __restrict__ src;
    unsigned short *hi, *lo;
    int n;
    if (seg == 0)      { src = a_z;  hi = ah; lo = al; n = NA * DIM; }
    else if (seg == 1) { src = bv_z; hi = bh; lo = bl; n = NB * DIM; }
    else {
        src = (seg == 2) ? Wq : ((seg == 3) ? Wk : Wv);
        hi = wparts + (seg - 2) * 2 * DIM * DIM;
        lo = hi + DIM * DIM;
        n = DIM * DIM;
    }
    const int i = (blockIdx.x * 256 + threadIdx.x) * 4;
    if (i >= n) return;
    f32x4 v = *(const f32x4*)(src + i);
    us4 h4, l4;
    #pragma unroll
    for (int r = 0; r < 4; ++r) {
        unsigned short h = f2bf(v[r]);
        h4[r] = h;
        l4[r] = f2bf(v[r] - bf2f(h));
    }
    *(us4*)(hi + i) = h4;
    *(us4*)(lo + i) = l4;
}

// ---------------------------------------------------------------------------
// Pack mask int32 -> bits (64 MB -> 2 MB). Row-major: bit b of byte
// mb[a*512 + b/8] = mask[a][b].
// ---------------------------------------------------------------------------
__global__ __launch_bounds__(256) void maskpack_kernel(
    const int* __restrict__ mg, unsigned char* __restrict__ mb)
{
    const int gid = blockIdx.x * 256 + threadIdx.x;   // 0 .. 2M-1
    const int base = gid * 8;
    i32x4 m0 = *(const i32x4*)(mg + base);
    i32x4 m1 = *(const i32x4*)(mg + base + 4);
    unsigned int b = 0;
    #pragma unroll
    for (int r = 0; r < 4; ++r) {
        b |= (unsigned int)(m0[r] != 0) << r;
        b |= (unsigned int)(m1[r] != 0) << (r + 4);
    }
    mb[gid] = (unsigned char)b;
}

// ---------------------------------------------------------------------------
// Projections, fp32-accurate via 3-term split MFMA.
// mat 0: q -> qhi (bf16); mat 1: k -> khi; mat 2: v -> vt (transposed).
// ---------------------------------------------------------------------------
__global__ __launch_bounds__(256) void proj_kernel(
    const unsigned short* __restrict__ ah, const unsigned short* __restrict__ al,
    const unsigned short* __restrict__ bh, const unsigned short* __restrict__ bl,
    const unsigned short* __restrict__ wparts,
    unsigned short* __restrict__ qhi,
    unsigned short* __restrict__ khi, unsigned short* __restrict__ vtout)
{
    const int mat = blockIdx.z;
    const unsigned short* __restrict__ XH = (mat == 0) ? ah : bh;
    const unsigned short* __restrict__ XL = (mat == 0) ? al : bl;
    const unsigned short* __restrict__ WH = wparts + mat * 2 * DIM * DIM;
    const unsigned short* __restrict__ WL = WH + DIM * DIM;

    const int tid  = threadIdx.x;
    const int wv   = tid >> 6;
    const int lane = tid & 63;
    const int c    = lane & 15;
    const int quad = lane >> 4;
    const int n0 = blockIdx.x * 64;
    const int j0 = blockIdx.y * 64 + wv * 16;

    f32x4 acc[4];
    #pragma unroll
    for (int nt = 0; nt < 4; ++nt) acc[nt] = (f32x4){0.f, 0.f, 0.f, 0.f};

    #pragma unroll
    for (int ki = 0; ki < 8; ++ki) {
        const int i0 = ki * 32 + quad * 8;
        bf16x8 wh = *(const bf16x8*)(WH + (j0 + c) * DIM + i0);
        bf16x8 wl = *(const bf16x8*)(WL + (j0 + c) * DIM + i0);
        #pragma unroll
        for (int nt = 0; nt < 4; ++nt) {
            const int row = (n0 + nt * 16 + c) * DIM + i0;
            bf16x8 xh = *(const bf16x8*)(XH + row);
            bf16x8 xl = *(const bf16x8*)(XL + row);
            acc[nt] = __builtin_amdgcn_mfma_f32_16x16x32_bf16(xh, wh, acc[nt], 0, 0, 0);
            acc[nt] = __builtin_amdgcn_mfma_f32_16x16x32_bf16(xl, wh, acc[nt], 0, 0, 0);
            acc[nt] = __builtin_amdgcn_mfma_f32_16x16x32_bf16(xh, wl, acc[nt], 0, 0, 0);
        }
    }

    if (mat == 0) {
        #pragma unroll
        for (int nt = 0; nt < 4; ++nt)
            #pragma unroll
            for (int r = 0; r < 4; ++r)
                qhi[(n0 + nt * 16 + quad * 4 + r) * DIM + j0 + c] = f2bf(acc[nt][r]);
    } else if (mat == 1) {
        #pragma unroll
        for (int nt = 0; nt < 4; ++nt)
            #pragma unroll
            for (int r = 0; r < 4; ++r)
                khi[(n0 + nt * 16 + quad * 4 + r) * DIM + j0 + c] = f2bf(acc[nt][r]);
    } else {
        #pragma unroll
        for (int nt = 0; nt < 4; ++nt) {
            us4 p;
            #pragma unroll
            for (int r = 0; r < 4; ++r) p[r] = f2bf(acc[nt][r]);
            *(us4*)(vtout + (j0 + c) * NB + n0 + nt * 16 + quad * 4) = p;
        }
    }
}

// ---------------------------------------------------------------------------
// Fused attention v3: NO LDS, NO barriers. 256 thr = 4 waves = 4 heads,
// grid (256 a-tiles, 8 b-splits). Per 64-b tile:
//   S^T = K·Q^T (16x16x32, C-layout a=lane&15, b=quad*4+r)
//   P = exp2(clip((S/8+w)*log2e)) with bit-mask select -> exp(-10)
//   PV via (PV)^T = V^T·P : P's C-layout IS the B-operand layout; V^T frag
//   from vt is the A operand. num stays in regs; partials written directly.
// w (float4) + mask-bits double-buffered one iter ahead (HBM-cold stream).
// ---------------------------------------------------------------------------
__global__ __launch_bounds__(256, 3) void attn_kernel(
    const unsigned short* __restrict__ qg,
    const unsigned short* __restrict__ kg,
    const unsigned short* __restrict__ vtg,
    const float* __restrict__ wg,
    const unsigned char* __restrict__ mb,
    float* __restrict__ pp)
{
    const int tid  = threadIdx.x;
    const int head = tid >> 6;
    const int lane = tid & 63;
    const int c    = lane & 15;
    const int quad = lane >> 4;
    const int t    = blockIdx.x;
    const int s    = blockIdx.y;
    const int a0   = t * 16;
    const int nit  = 8;                 // 64 b-tiles / 8 splits

    bf16x8 qh[2];
    #pragma unroll
    for (int ks = 0; ks < 2; ++ks)
        qh[ks] = *(const bf16x8*)(qg + (a0 + c) * DIM + head * DK + ks * 32 + quad * 8);

    f32x4 num[4];
    #pragma unroll
    for (int nt = 0; nt < 4; ++nt) num[nt] = (f32x4){0.f, 0.f, 0.f, 0.f};
    float den = 0.0f;

    struct WBuf { f32x4 wf[4]; uint2 mc; };

    auto loadW = [&](int it, WBuf& b) {
        const int b0 = it * 64;
        #pragma unroll
        for (int bt = 0; bt < 4; ++bt)
            b.wf[bt] = *(const f32x4*)(wg + (size_t)(a0 + c) * NB + b0 + bt * 16 + quad * 4);
        b.mc = *(const uint2*)(mb + (a0 + c) * (NB / 8) + (b0 >> 3));
    };

    auto compute = [&](int it, const WBuf& wb) {
        const int b0 = it * 64;

        bf16x8 kf[4][2];
        #pragma unroll
        for (int bt = 0; bt < 4; ++bt)
            #pragma unroll
            for (int ks = 0; ks < 2; ++ks)
                kf[bt][ks] = *(const bf16x8*)(kg + (b0 + bt * 16 + c) * DIM + head * DK + ks * 32 + quad * 8);

        us4 vfr[4][4];   // [nt][bt], 8B each, vt row-contiguous along b
        #pragma unroll
        for (int nt = 0; nt < 4; ++nt)
            #pragma unroll
            for (int bt = 0; bt < 4; ++bt)
                vfr[nt][bt] = *(const us4*)(vtg + (size_t)(head * DK + nt * 16 + c) * NB + b0 + bt * 16 + quad * 4);

        // S^T[b][a] = K·Q^T
        f32x4 S[4];
        #pragma unroll
        for (int bt = 0; bt < 4; ++bt) {
            f32x4 sv = (f32x4){0.f, 0.f, 0.f, 0.f};
            sv = __builtin_amdgcn_mfma_f32_16x16x32_bf16(kf[bt][0], qh[0], sv, 0, 0, 0);
            sv = __builtin_amdgcn_mfma_f32_16x16x32_bf16(kf[bt][1], qh[1], sv, 0, 0, 0);
            S[bt] = sv;
        }

        // elementwise in log2 space; lane holds (a=c, b=bt*16+quad*4+r)
        unsigned int pk[4][2];
        float dl = 0.0f;
        #pragma unroll
        for (int bt = 0; bt < 4; ++bt) {
            const unsigned int mchunk = (bt & 2) ? wb.mc.y : wb.mc.x;
            float e[4];
            #pragma unroll
            for (int r = 0; r < 4; ++r) {
                float tt = fmaf(S[bt][r], 0.125f, wb.wf[bt][r]) * LOG2E;
                tt = __builtin_amdgcn_fmed3f(tt, -CLIP2, CLIP2);
                float ev = exp2f(tt);
                const unsigned int bit = (mchunk >> ((bt & 1) * 16 + quad * 4 + r)) & 1u;
                ev = bit ? ev : EXPM10;
                e[r] = ev;
                dl += ev;
            }
            const unsigned int u0 = asuint(e[0]) + 0x8000u;
            const unsigned int u1 = asuint(e[1]) + 0x8000u;
            const unsigned int u2 = asuint(e[2]) + 0x8000u;
            const unsigned int u3 = asuint(e[3]) + 0x8000u;
            pk[bt][0] = (u1 & 0xffff0000u) | (u0 >> 16);
            pk[bt][1] = (u3 & 0xffff0000u) | (u2 >> 16);
        }
        den += dl;

        // PV: (PV)^T = V^T · P, bt-pairs packed into K=32
        #pragma unroll
        for (int pr = 0; pr < 2; ++pr) {
            const int btA = pr * 2, btB = pr * 2 + 1;
            union { unsigned int u[4]; bf16x8 v; } P;
            P.u[0] = pk[btA][0]; P.u[1] = pk[btA][1];
            P.u[2] = pk[btB][0]; P.u[3] = pk[btB][1];
            #pragma unroll
            for (int nt = 0; nt < 4; ++nt) {
                union { us4 h[2]; bf16x8 v; } A;
                A.h[0] = vfr[nt][btA];
                A.h[1] = vfr[nt][btB];
                num[nt] = __builtin_amdgcn_mfma_f32_16x16x32_bf16(A.v, P.v, num[nt], 0, 0, 0);
            }
        }
    };

    WBuf w0, w1;
    int it = s * nit;
    const int itEnd = it + nit;
    loadW(it, w0);
    while (true) {
        if (it + 1 < itEnd) loadW(it + 1, w1);
        compute(it, w0);
        if (++it == itEnd) break;
        if (it + 1 < itEnd) loadW(it + 1, w0);
        compute(it, w1);
        if (++it == itEnd) break;
    }

    // den across quads (same a = c)
    den += __shfl_xor(den, 16, 64);
    den += __shfl_xor(den, 32, 64);

    // partials straight from registers: num (PV)^T -> [a=c][d=nt*16+quad*4+r]
    float* base = pp + ((size_t)(t * 8 + s) * 4 + head) * PBLK;
    #pragma unroll
    for (int nt = 0; nt < 4; ++nt)
        *(f32x4*)(base + c * 64 + nt * 16 + quad * 4) = num[nt];
    if (lane < 16) base[1024 + lane] = den;
}

// ---------------------------------------------------------------------------
// Combine partials: out[a][dd] = 0.25 * sum_h (sum_s num)/(sum_s den).
// influence == 1.0 analytically (softmax rows sum to 1).
// ---------------------------------------------------------------------------
__global__ __launch_bounds__(256) void reduce_kernel(
    const float* __restrict__ pp, float* __restrict__ outp, int SPLIT)
{
    const int gid = blockIdx.x * 256 + threadIdx.x;   // 0 .. 262143
    const int a = gid >> 6, dd = gid & 63;
    const int t = a >> 4, ar = a & 15;
    float acc = 0.0f;
    #pragma unroll
    for (int h = 0; h < 4; ++h) {
        float n = 0.0f, d = 0.0f;
        for (int ss = 0; ss < SPLIT; ++ss) {
            const float* base = pp + ((size_t)(t * SPLIT + ss) * 4 + h) * PBLK;
            n += base[ar * 64 + dd];
            d += base[1024 + ar];
        }
        acc += n / d;
    }
    outp[a * DK + dd] = 0.25f * acc;
    if (dd == 0) outp[NA * DK + a] = 1.0f;
}

extern "C" void kernel_launch(void* const* d_in, const int* in_sizes, int n_in,
                              void* d_out, int out_size, void* d_ws, size_t ws_size,
                              hipStream_t stream) {
    const float* a_z = (const float*)d_in[0];
    const float* bv  = (const float*)d_in[1];
    const int* mask  = (const int*)d_in[2];
    const float* wgt = (const float*)d_in[3];
    const float* Wq  = (const float*)d_in[4];
    const float* Wk  = (const float*)d_in[5];
    const float* Wv  = (const float*)d_in[6];
    float* out = (float*)d_out;

    const size_t NE = (size_t)NA * DIM;               // 1,048,576 elems
    // persistent: qhi 2MB | khi 2MB | vt 2MB | mb 2MB | pp 34MB  = 42 MB
    unsigned short* qhi = (unsigned short*)d_ws;
    unsigned short* khi = qhi + NE;
    unsigned short* vt  = khi + NE;
    unsigned char*  mb  = (unsigned char*)(vt + NE);
    float* pp = (float*)(mb + (size_t)NA * (NB / 8));
    // transients (dead before attn writes pp): ah/al/bh/bl + wparts inside pp
    unsigned short* ah = (unsigned short*)pp;
    unsigned short* al = ah + NE;
    unsigned short* bh = al + NE;
    unsigned short* bl = bh + NE;
    unsigned short* wparts = bl + NE;                 // 6 * 65536 elems

    split_kernel<<<dim3(1024, 5), 256, 0, stream>>>(a_z, bv, Wq, Wk, Wv,
                                                    ah, al, bh, bl, wparts);
    proj_kernel<<<dim3(64, 4, 3), 256, 0, stream>>>(ah, al, bh, bl, wparts,
                                                    qhi, khi, vt);
    maskpack_kernel<<<dim3((NA * NB / 8) / 256), 256, 0, stream>>>(mask, mb);
    attn_kernel<<<dim3(256, 8), 256, 0, stream>>>(qhi, khi, vt, wgt, mb, pp);
    reduce_kernel<<<dim3(1024), 256, 0, stream>>>(pp, out, 8);
}

// Round 7
// 394.111 us; speedup vs baseline: 1.0010x; 1.0010x over previous
//
#include <hip/hip_runtime.h>

#define NA 4096
#define NB 4096
#define DIM 256
#define DK 64
#define PBLK 1040        // partial block: 16*64 num + 16 den (floats)
#define LOG2E 1.4426950408889634f
#define CLIP2 14.426950408889634f          // 10 * log2(e)
#define KSCALE 0.18033688011116042f        // 0.125 * log2(e)
#define WMASKED -14426.950408889634f       // -10000 * log2(e); clips to -CLIP2

typedef __attribute__((ext_vector_type(8))) short bf16x8;
typedef __attribute__((ext_vector_type(4))) float f32x4;
typedef __attribute__((ext_vector_type(4))) unsigned short us4;
typedef __attribute__((ext_vector_type(4))) int i32x4;
typedef __attribute__((ext_vector_type(4))) unsigned int u32x4;

static __device__ __forceinline__ float bf2f(unsigned short u) {
    union { unsigned int u; float f; } x;
    x.u = ((unsigned int)u) << 16;
    return x.f;
}
static __device__ __forceinline__ unsigned short f2bf(float f) {
    union { float f; unsigned int u; } x;
    x.f = f;
    unsigned int r = x.u + 0x7fffu + ((x.u >> 16) & 1u);
    return (unsigned short)(r >> 16);
}
static __device__ __forceinline__ unsigned int asuint(float f) {
    union { float f; unsigned int u; } x; x.f = f; return x.u;
}

// ---------------------------------------------------------------------------
// Pre-split: fp32 -> bf16 hi + lo correction, coalesced elementwise.
// ---------------------------------------------------------------------------
__global__ __launch_bounds__(256) void split_kernel(
    const float* __restrict__ a_z, const float* __restrict__ bv_z,
    const float* __restrict__ Wq, const float* __restrict__ Wk,
    const float* __restrict__ Wv,
    unsigned short* __restrict__ ah, unsigned short* __restrict__ al,
    unsigned short* __restrict__ bh, unsigned short* __restrict__ bl,
    unsigned short* __restrict__ wparts)
{
    const int seg = blockIdx.y;
    const float* __restrict__ src;
    unsigned short *hi, *lo;
    int n;
    if (seg == 0)      { src = a_z;  hi = ah; lo = al; n = NA * DIM; }
    else if (seg == 1) { src = bv_z; hi = bh; lo = bl; n = NB * DIM; }
    else {
        src = (seg == 2) ? Wq : ((seg == 3) ? Wk : Wv);
        hi = wparts + (seg - 2) * 2 * DIM * DIM;
        lo = hi + DIM * DIM;
        n = DIM * DIM;
    }
    const int i = (blockIdx.x * 256 + threadIdx.x) * 4;
    if (i >= n) return;
    f32x4 v = *(const f32x4*)(src + i);
    us4 h4, l4;
    #pragma unroll
    for (int r = 0; r < 4; ++r) {
        unsigned short h = f2bf(v[r]);
        h4[r] = h;
        l4[r] = f2bf(v[r] - bf2f(h));
    }
    *(us4*)(hi + i) = h4;
    *(us4*)(lo + i) = l4;
}

// ---------------------------------------------------------------------------
// Repack weight+mask into attn consume-order fp16 tiles (the R6 killer was
// w's 64B-granule 16KB-strided HBM scatter at 400 GB/s).
// Tile (t, it) = w[16a x 64b] * log2e, masked -> WMASKED (clip makes it -10).
// In-tile layout matches lane consumption: p = a*64 + quad*16 + bt*4 + r
// (b = bt*16 + quad*4 + r), so each attn lane reads 32B contiguous.
// Reads fully coalesced; writes 8B-granular within contiguous 2KB tiles.
// ---------------------------------------------------------------------------
__global__ __launch_bounds__(256) void wrepack_kernel(
    const float* __restrict__ wg, const int* __restrict__ mg,
    unsigned short* __restrict__ wp)
{
    const int gid = blockIdx.x * 256 + threadIdx.x;   // 0 .. 4M-1
    const int a  = gid >> 10;
    const int bq = (gid & 1023) << 2;
    f32x4 w4 = *(const f32x4*)(wg + (size_t)a * NB + bq);
    i32x4 m4 = *(const i32x4*)(mg + (size_t)a * NB + bq);
    us4 h4;
    #pragma unroll
    for (int r = 0; r < 4; ++r) {
        float v = m4[r] ? w4[r] * LOG2E : WMASKED;
        union { unsigned short s; _Float16 h; } cv;
        cv.h = (_Float16)v;
        h4[r] = cv.s;
    }
    const size_t p = ((size_t)(a >> 4) * 64 + (bq >> 6)) * 1024
                   + (a & 15) * 64 + ((bq >> 2) & 3) * 16 + ((bq >> 4) & 3) * 4;
    *(us4*)(wp + p) = h4;
}

// ---------------------------------------------------------------------------
// Projections, fp32-accurate via 3-term split MFMA.
// mat 0: q -> qhi (bf16); mat 1: k -> khi; mat 2: v -> vt (transposed).
// ---------------------------------------------------------------------------
__global__ __launch_bounds__(256) void proj_kernel(
    const unsigned short* __restrict__ ah, const unsigned short* __restrict__ al,
    const unsigned short* __restrict__ bh, const unsigned short* __restrict__ bl,
    const unsigned short* __restrict__ wparts,
    unsigned short* __restrict__ qhi,
    unsigned short* __restrict__ khi, unsigned short* __restrict__ vtout)
{
    const int mat = blockIdx.z;
    const unsigned short* __restrict__ XH = (mat == 0) ? ah : bh;
    const unsigned short* __restrict__ XL = (mat == 0) ? al : bl;
    const unsigned short* __restrict__ WH = wparts + mat * 2 * DIM * DIM;
    const unsigned short* __restrict__ WL = WH + DIM * DIM;

    const int tid  = threadIdx.x;
    const int wv   = tid >> 6;
    const int lane = tid & 63;
    const int c    = lane & 15;
    const int quad = lane >> 4;
    const int n0 = blockIdx.x * 64;
    const int j0 = blockIdx.y * 64 + wv * 16;

    f32x4 acc[4];
    #pragma unroll
    for (int nt = 0; nt < 4; ++nt) acc[nt] = (f32x4){0.f, 0.f, 0.f, 0.f};

    #pragma unroll
    for (int ki = 0; ki < 8; ++ki) {
        const int i0 = ki * 32 + quad * 8;
        bf16x8 wh = *(const bf16x8*)(WH + (j0 + c) * DIM + i0);
        bf16x8 wl = *(const bf16x8*)(WL + (j0 + c) * DIM + i0);
        #pragma unroll
        for (int nt = 0; nt < 4; ++nt) {
            const int row = (n0 + nt * 16 + c) * DIM + i0;
            bf16x8 xh = *(const bf16x8*)(XH + row);
            bf16x8 xl = *(const bf16x8*)(XL + row);
            acc[nt] = __builtin_amdgcn_mfma_f32_16x16x32_bf16(xh, wh, acc[nt], 0, 0, 0);
            acc[nt] = __builtin_amdgcn_mfma_f32_16x16x32_bf16(xl, wh, acc[nt], 0, 0, 0);
            acc[nt] = __builtin_amdgcn_mfma_f32_16x16x32_bf16(xh, wl, acc[nt], 0, 0, 0);
        }
    }

    if (mat == 0) {
        #pragma unroll
        for (int nt = 0; nt < 4; ++nt)
            #pragma unroll
            for (int r = 0; r < 4; ++r)
                qhi[(n0 + nt * 16 + quad * 4 + r) * DIM + j0 + c] = f2bf(acc[nt][r]);
    } else if (mat == 1) {
        #pragma unroll
        for (int nt = 0; nt < 4; ++nt)
            #pragma unroll
            for (int r = 0; r < 4; ++r)
                khi[(n0 + nt * 16 + quad * 4 + r) * DIM + j0 + c] = f2bf(acc[nt][r]);
    } else {
        #pragma unroll
        for (int nt = 0; nt < 4; ++nt) {
            us4 p;
            #pragma unroll
            for (int r = 0; r < 4; ++r) p[r] = f2bf(acc[nt][r]);
            *(us4*)(vtout + (j0 + c) * NB + n0 + nt * 16 + quad * 4) = p;
        }
    }
}

// ---------------------------------------------------------------------------
// Fused attention v4: no LDS/barriers; w read as sequential fp16 tiles with a
// 4-buffer rotating register prefetch (load->use distance = 3 iterations).
// Mask is pre-fused into wpack. k/vt/q are L2-resident.
// ---------------------------------------------------------------------------
struct WF { u32x4 x, y; };

__global__ __launch_bounds__(256, 3) void attn_kernel(
    const unsigned short* __restrict__ qg,
    const unsigned short* __restrict__ kg,
    const unsigned short* __restrict__ vtg,
    const unsigned short* __restrict__ wp,
    float* __restrict__ pp)
{
    const int tid  = threadIdx.x;
    const int head = tid >> 6;
    const int lane = tid & 63;
    const int c    = lane & 15;
    const int quad = lane >> 4;
    const int t    = blockIdx.x;
    const int s    = blockIdx.y;
    const int SPLIT = gridDim.y;
    const int nit  = 64 / SPLIT;
    const int it0  = s * nit;
    const int a0   = t * 16;

    const unsigned short* wbase = wp + ((size_t)t * 64 + it0) * 1024 + (c * 4 + quad) * 16;

    bf16x8 qh[2];
    #pragma unroll
    for (int ks = 0; ks < 2; ++ks)
        qh[ks] = *(const bf16x8*)(qg + (a0 + c) * DIM + head * DK + ks * 32 + quad * 8);

    f32x4 num[4];
    #pragma unroll
    for (int nt = 0; nt < 4; ++nt) num[nt] = (f32x4){0.f, 0.f, 0.f, 0.f};
    float den = 0.0f;

    auto loadw = [&](int j) -> WF {
        const unsigned short* p = wbase + (size_t)j * 1024;
        WF w;
        w.x = *(const u32x4*)p;
        w.y = *(const u32x4*)(p + 8);
        return w;
    };

    auto compute = [&](int j, const WF& wf) {
        const int b0 = (it0 + j) * 64;

        bf16x8 kf[4][2];
        #pragma unroll
        for (int bt = 0; bt < 4; ++bt)
            #pragma unroll
            for (int ks = 0; ks < 2; ++ks)
                kf[bt][ks] = *(const bf16x8*)(kg + (b0 + bt * 16 + c) * DIM + head * DK + ks * 32 + quad * 8);

        us4 vfr[4][4];
        #pragma unroll
        for (int nt = 0; nt < 4; ++nt)
            #pragma unroll
            for (int bt = 0; bt < 4; ++bt)
                vfr[nt][bt] = *(const us4*)(vtg + (size_t)(head * DK + nt * 16 + c) * NB + b0 + bt * 16 + quad * 4);

        // S^T[b][a] = K·Q^T  (C-layout: a = c, b = quad*4 + r within bt-subtile)
        f32x4 S[4];
        #pragma unroll
        for (int bt = 0; bt < 4; ++bt) {
            f32x4 sv = (f32x4){0.f, 0.f, 0.f, 0.f};
            sv = __builtin_amdgcn_mfma_f32_16x16x32_bf16(kf[bt][0], qh[0], sv, 0, 0, 0);
            sv = __builtin_amdgcn_mfma_f32_16x16x32_bf16(kf[bt][1], qh[1], sv, 0, 0, 0);
            S[bt] = sv;
        }

        // P = exp2(med3(S*kscale + w_l2e, +-CLIP2)); mask pre-fused into w
        unsigned int pk[4][2];
        float dl = 0.0f;
        #pragma unroll
        for (int bt = 0; bt < 4; ++bt) {
            float e[4];
            #pragma unroll
            for (int r = 0; r < 4; ++r) {
                const int eidx = bt * 4 + r;
                const unsigned int word = (eidx < 8) ? wf.x[eidx >> 1] : wf.y[(eidx >> 1) - 4];
                union { unsigned short s; _Float16 h; } cv;
                cv.s = (eidx & 1) ? (unsigned short)(word >> 16) : (unsigned short)(word & 0xffffu);
                float tt = fmaf(S[bt][r], KSCALE, (float)cv.h);
                tt = __builtin_amdgcn_fmed3f(tt, -CLIP2, CLIP2);
                float ev = exp2f(tt);
                e[r] = ev;
                dl += ev;
            }
            const unsigned int u0 = asuint(e[0]) + 0x8000u;
            const unsigned int u1 = asuint(e[1]) + 0x8000u;
            const unsigned int u2 = asuint(e[2]) + 0x8000u;
            const unsigned int u3 = asuint(e[3]) + 0x8000u;
            pk[bt][0] = (u1 & 0xffff0000u) | (u0 >> 16);
            pk[bt][1] = (u3 & 0xffff0000u) | (u2 >> 16);
        }
        den += dl;

        // PV: (PV)^T = V^T · P; both operands use the same permuted-K map
        #pragma unroll
        for (int pr = 0; pr < 2; ++pr) {
            const int btA = pr * 2, btB = pr * 2 + 1;
            union { unsigned int u[4]; bf16x8 v; } P;
            P.u[0] = pk[btA][0]; P.u[1] = pk[btA][1];
            P.u[2] = pk[btB][0]; P.u[3] = pk[btB][1];
            #pragma unroll
            for (int nt = 0; nt < 4; ++nt) {
                union { us4 h[2]; bf16x8 v; } A;
                A.h[0] = vfr[nt][btA];
                A.h[1] = vfr[nt][btB];
                num[nt] = __builtin_amdgcn_mfma_f32_16x16x32_bf16(A.v, P.v, num[nt], 0, 0, 0);
            }
        }
    };

    const int last = nit - 1;
    WF w0 = loadw(0), w1 = loadw(1), w2 = loadw(2), w3 = loadw(3);
    for (int j = 0; j < nit; j += 4) {
        compute(j + 0, w0); w0 = loadw(j + 4 > last ? last : j + 4);
        compute(j + 1, w1); w1 = loadw(j + 5 > last ? last : j + 5);
        compute(j + 2, w2); w2 = loadw(j + 6 > last ? last : j + 6);
        compute(j + 3, w3); w3 = loadw(j + 7 > last ? last : j + 7);
    }

    // den across quads (same a = c)
    den += __shfl_xor(den, 16, 64);
    den += __shfl_xor(den, 32, 64);

    // partials from registers: num (PV)^T -> [a=c][d = nt*16 + quad*4 + r]
    float* base = pp + ((size_t)(t * SPLIT + s) * 4 + head) * PBLK;
    #pragma unroll
    for (int nt = 0; nt < 4; ++nt)
        *(f32x4*)(base + c * 64 + nt * 16 + quad * 4) = num[nt];
    if (lane < 16) base[1024 + lane] = den;
}

// ---------------------------------------------------------------------------
// Combine partials: out[a][dd] = 0.25 * sum_h (sum_s num)/(sum_s den).
// influence == 1.0 analytically (softmax rows sum to 1).
// ---------------------------------------------------------------------------
__global__ __launch_bounds__(256) void reduce_kernel(
    const float* __restrict__ pp, float* __restrict__ outp, int SPLIT)
{
    const int gid = blockIdx.x * 256 + threadIdx.x;   // 0 .. 262143
    const int a = gid >> 6, dd = gid & 63;
    const int t = a >> 4, ar = a & 15;
    float acc = 0.0f;
    #pragma unroll
    for (int h = 0; h < 4; ++h) {
        float n = 0.0f, d = 0.0f;
        for (int ss = 0; ss < SPLIT; ++ss) {
            const float* base = pp + ((size_t)(t * SPLIT + ss) * 4 + h) * PBLK;
            n += base[ar * 64 + dd];
            d += base[1024 + ar];
        }
        acc += n / d;
    }
    outp[a * DK + dd] = 0.25f * acc;
    if (dd == 0) outp[NA * DK + a] = 1.0f;
}

extern "C" void kernel_launch(void* const* d_in, const int* in_sizes, int n_in,
                              void* d_out, int out_size, void* d_ws, size_t ws_size,
                              hipStream_t stream) {
    const float* a_z = (const float*)d_in[0];
    const float* bv  = (const float*)d_in[1];
    const int* mask  = (const int*)d_in[2];
    const float* wgt = (const float*)d_in[3];
    const float* Wq  = (const float*)d_in[4];
    const float* Wk  = (const float*)d_in[5];
    const float* Wv  = (const float*)d_in[6];
    float* out = (float*)d_out;

    const size_t NE = (size_t)NA * DIM;               // 1,048,576 elems
    // persistent: qhi 2MB | khi 2MB | vt 2MB | wpack 32MB | pp (SPLIT*4.26MB)
    unsigned short* qhi = (unsigned short*)d_ws;
    unsigned short* khi = qhi + NE;
    unsigned short* vt  = khi + NE;
    unsigned short* wpk = vt + NE;                    // NA*NB fp16 = 32 MB
    float* pp = (float*)(wpk + (size_t)NA * NB);
    // transients (dead before wrepack writes wpk): alias the wpack region
    unsigned short* ah = wpk;
    unsigned short* al = ah + NE;
    unsigned short* bh = al + NE;
    unsigned short* bl = bh + NE;
    unsigned short* wparts = bl + NE;                 // 6 * 65536 elems

    const size_t fixed = (char*)pp - (char*)d_ws;     // ~38 MB
    const size_t ppS = (size_t)256 * 4 * PBLK * 4;    // per-split pp bytes
    int SPLIT = 1;
    if (ws_size >= fixed + 4 * ppS) SPLIT = 4;
    else if (ws_size >= fixed + 2 * ppS) SPLIT = 2;

    split_kernel<<<dim3(1024, 5), 256, 0, stream>>>(a_z, bv, Wq, Wk, Wv,
                                                    ah, al, bh, bl, wparts);
    proj_kernel<<<dim3(64, 4, 3), 256, 0, stream>>>(ah, al, bh, bl, wparts,
                                                    qhi, khi, vt);
    wrepack_kernel<<<dim3((NA / 1) * (NB / 1024)), 256, 0, stream>>>(wgt, mask, wpk);
    attn_kernel<<<dim3(256, SPLIT), 256, 0, stream>>>(qhi, khi, vt, wpk, pp);
    reduce_kernel<<<dim3(1024), 256, 0, stream>>>(pp, out, SPLIT);
}